// Round 7
// baseline (81.866 us; speedup 1.0000x reference)
//
#include <hip/hip_runtime.h>

#define BB 64
#define CC 64
#define TT 8192
#define NB 8

typedef __attribute__((ext_vector_type(8))) short bf16x8;
typedef __attribute__((ext_vector_type(4))) float f32x4;
typedef __attribute__((ext_vector_type(4))) int i32x4;

union I4B8 { i32x4 i; bf16x8 b; };

__device__ __forceinline__ unsigned short f32_to_bf16_rn(float f) {
    unsigned u = __float_as_uint(f);
    unsigned r = (u + 0x7FFFu + ((u >> 16) & 1u)) >> 16;
    return (unsigned short)r;
}
__device__ __forceinline__ float bf16_to_f32(unsigned short h) {
    return __uint_as_float(((unsigned)h) << 16);
}

// ---- prep: W[p][c] bf16 hi/lo (round-to-nearest), p<32 = scaled E, p>=32 = F
__global__ __launch_bounds__(256) void rpg_prep(
    const float* __restrict__ sigma, const float* __restrict__ rho,
    const float* __restrict__ E, const float* __restrict__ F,
    unsigned short* __restrict__ Whi, unsigned short* __restrict__ Wlo)
{
    const int j = blockIdx.x * 256 + threadIdx.x;
    if (j >= 64 * CC) return;
    const int p = j >> 6;
    const int c = j & 63;
    float val;
    if (p < 32) {
        const int r = p >> 3, n = p & 7;
        const float es = 8.0f / (1e-5f + fabsf(sigma[r]));
        const float fs = 8.0f / (1e-5f + fabsf(rho[r]));
        val = E[r * (CC * NB) + c * NB + n] * (es * fs * 0.25f);
    } else {
        const int r = (p - 32) >> 3, n = p & 7;
        val = F[r * (CC * NB) + c * NB + n];
    }
    const unsigned short h = f32_to_bf16_rn(val);
    Whi[p * CC + c] = h;
    Wlo[p * CC + c] = f32_to_bf16_rn(val - bf16_to_f32(h));
}

// ---- main: one wave = one (b, 16-t tile), all 64 output rows. No LDS, no barriers.
__global__ __launch_bounds__(256, 3) void rpg_main(
    const float* __restrict__ x,
    const unsigned short* __restrict__ Whi,
    const unsigned short* __restrict__ Wlo,
    float* __restrict__ out)
{
    const int tid  = threadIdx.x;
    const int w    = tid >> 6;
    const int lane = tid & 63;
    const int am   = lane & 15;      // t within tile; MFMA B col / D col
    const int ag   = lane >> 4;      // k-group

    const int b    = blockIdx.x >> 7;
    const int tile = (blockIdx.x & 127) * 4 + w;     // 512 tiles of 16 t per b
    const int t0   = tile * 16;

    // ---- load x B-frags straight from global, convert to bf16 hi/lo in regs
    // B-frag (16x16x32): lane holds x[c = ks*32 + ag*8 + j][t0 + am], j=0..7
    const float* xb = x + b * (CC * TT) + t0 + am;
    bf16x8 xh[2], xl[2];
    #pragma unroll
    for (int ks = 0; ks < 2; ++ks) {
        float f[8];
        #pragma unroll
        for (int j = 0; j < 8; ++j)
            f[j] = xb[(ks * 32 + ag * 8 + j) * TT];
        unsigned hw[4], lw[4];
        #pragma unroll
        for (int k = 0; k < 4; ++k) {
            const unsigned u0 = __float_as_uint(f[2 * k]);
            const unsigned u1 = __float_as_uint(f[2 * k + 1]);
            hw[k] = (u0 >> 16) | (u1 & 0xFFFF0000u);
            const float h0 = __uint_as_float(u0 & 0xFFFF0000u);
            const float h1 = __uint_as_float(u1 & 0xFFFF0000u);
            lw[k] = (__float_as_uint(f[2 * k] - h0) >> 16) |
                    (__float_as_uint(f[2 * k + 1] - h1) & 0xFFFF0000u);
        }
        I4B8 H, L;
        H.i = (i32x4){(int)hw[0], (int)hw[1], (int)hw[2], (int)hw[3]};
        L.i = (i32x4){(int)lw[0], (int)lw[1], (int)lw[2], (int)lw[3]};
        xh[ks] = H.b;
        xl[ks] = L.b;
    }

    // ---- GEMM: acc[mt][r] = Y[p = mt*16 + ag*4 + r][t0 + am], 3-pass hi/lo
    f32x4 acc[4];
    #pragma unroll
    for (int mt = 0; mt < 4; ++mt) {
        acc[mt] = (f32x4){0.0f, 0.0f, 0.0f, 0.0f};
        #pragma unroll
        for (int ks = 0; ks < 2; ++ks) {
            const int woff = (mt * 16 + am) * CC + ks * 32 + ag * 8;
            const bf16x8 wh = *(const bf16x8*)(Whi + woff);
            const bf16x8 wl = *(const bf16x8*)(Wlo + woff);
            acc[mt] = __builtin_amdgcn_mfma_f32_16x16x32_bf16(wh, xh[ks], acc[mt], 0, 0, 0);
            acc[mt] = __builtin_amdgcn_mfma_f32_16x16x32_bf16(wh, xl[ks], acc[mt], 0, 0, 0);
            acc[mt] = __builtin_amdgcn_mfma_f32_16x16x32_bf16(wl, xh[ks], acc[mt], 0, 0, 0);
        }
    }

    // ---- in-register epilogue --------------------------------------------
    // Y rows held by lane(ag): xe ranks {ra, ra+2} at cols 4*qsel + (0..3),
    // xf same. ra = ag>>1; qsel = ag&1. Partner l^32 has ranks {ra^1, ...};
    // partner l^16 has the other col-half.
    const bool ra0 = (ag & 2) == 0;        // ra == 0
    const bool qlo = (ag & 1) == 0;        // cols 0..3 if true

    // xor-32 exchange: partner's acc[0..3][i]
    float pA[4], pB[4], pC[4], pD[4];
    #pragma unroll
    for (int i = 0; i < 4; ++i) {
        pA[i] = __shfl_xor(acc[0][i], 32);
        pB[i] = __shfl_xor(acc[1][i], 32);
        pC[i] = __shfl_xor(acc[2][i], 32);
        pD[i] = __shfl_xor(acc[3][i], 32);
    }

    // xe: full ranks 0..3 at this lane's two n-cols (col index i = 2*ra + e)
    float xe_[4][2];
    #pragma unroll
    for (int e = 0; e < 2; ++e) {
        xe_[0][e] = ra0 ? acc[0][e] : pA[2 + e];
        xe_[1][e] = ra0 ? pA[e]     : acc[0][2 + e];
        xe_[2][e] = ra0 ? acc[1][e] : pB[2 + e];
        xe_[3][e] = ra0 ? pB[e]     : acc[1][2 + e];
    }

    // xf: full ranks at own col-quad
    float xfq0[4], xfq1[4], xfq2[4], xfq3[4];
    #pragma unroll
    for (int i = 0; i < 4; ++i) {
        xfq0[i] = ra0 ? acc[2][i] : pC[i];
        xfq1[i] = ra0 ? pC[i]     : acc[2][i];
        xfq2[i] = ra0 ? acc[3][i] : pD[i];
        xfq3[i] = ra0 ? pD[i]     : acc[3][i];
    }
    // xor-16: other col-quad
    float xfo0[4], xfo1[4], xfo2[4], xfo3[4];
    #pragma unroll
    for (int i = 0; i < 4; ++i) {
        xfo0[i] = __shfl_xor(xfq0[i], 16);
        xfo1[i] = __shfl_xor(xfq1[i], 16);
        xfo2[i] = __shfl_xor(xfq2[i], 16);
        xfo3[i] = __shfl_xor(xfq3[i], 16);
    }
    // absolute m: low quad (m = 0..3), high quad (m = 4..7)
    float xfL[4][4], xfH[4][4];
    #pragma unroll
    for (int i = 0; i < 4; ++i) {
        xfL[0][i] = qlo ? xfq0[i] : xfo0[i];  xfH[0][i] = qlo ? xfo0[i] : xfq0[i];
        xfL[1][i] = qlo ? xfq1[i] : xfo1[i];  xfH[1][i] = qlo ? xfo1[i] : xfq1[i];
        xfL[2][i] = qlo ? xfq2[i] : xfo2[i];  xfH[2][i] = qlo ? xfo2[i] : xfq2[i];
        xfL[3][i] = qlo ? xfq3[i] : xfo3[i];  xfH[3][i] = qlo ? xfo3[i] : xfq3[i];
    }

    // z[e][m] for n = 4*(ag&1) + 2*ra + e, all m
    float z[2][8];
    float pm = 0.0f;
    #pragma unroll
    for (int e = 0; e < 2; ++e) {
        #pragma unroll
        for (int m = 0; m < 4; ++m) {
            float a = xe_[0][e] * xfL[0][m];
            a = fmaf(xe_[1][e], xfL[1][m], a);
            a = fmaf(xe_[2][e], xfL[2][m], a);
            a = fmaf(xe_[3][e], xfL[3][m], a);
            float s = __builtin_amdgcn_sqrtf(fabsf(a) + 0.01f) - 0.1f;
            float v = copysignf(s, a);
            z[e][m] = v;
            pm = fmaxf(pm, fabsf(v));
        }
        #pragma unroll
        for (int m = 0; m < 4; ++m) {
            float a = xe_[0][e] * xfH[0][m];
            a = fmaf(xe_[1][e], xfH[1][m], a);
            a = fmaf(xe_[2][e], xfH[2][m], a);
            a = fmaf(xe_[3][e], xfH[3][m], a);
            float s = __builtin_amdgcn_sqrtf(fabsf(a) + 0.01f) - 0.1f;
            float v = copysignf(s, a);
            z[e][4 + m] = v;
            pm = fmaxf(pm, fabsf(v));
        }
    }

    // max over the full t-column: reduce across the 4-lane group {am, +16, +32, +48}
    pm = fmaxf(pm, __shfl_xor(pm, 16));
    pm = fmaxf(pm, __shfl_xor(pm, 32));
    const float rinv = __builtin_amdgcn_rcpf(pm + 1e-5f);

    const int nbase = (qlo ? 0 : 4) + (ra0 ? 0 : 2);
    float* ob = out + b * (64 * TT) + t0 + am;
    #pragma unroll
    for (int e = 0; e < 2; ++e)
        #pragma unroll
        for (int m = 0; m < 8; ++m)
            ob[((nbase + e) * NB + m) * TT] = z[e][m] * rinv;
}

extern "C" void kernel_launch(void* const* d_in, const int* in_sizes, int n_in,
                              void* d_out, int out_size, void* d_ws, size_t ws_size,
                              hipStream_t stream) {
    const float* x     = (const float*)d_in[0];
    const float* sigma = (const float*)d_in[1];
    const float* rho   = (const float*)d_in[2];
    const float* E     = (const float*)d_in[3];
    const float* F     = (const float*)d_in[4];
    float* out = (float*)d_out;

    unsigned short* Whi = (unsigned short*)d_ws;            // 8 KB
    unsigned short* Wlo = Whi + 64 * CC;                    // 8 KB

    rpg_prep<<<(64 * CC + 255) / 256, 256, 0, stream>>>(sigma, rho, E, F, Whi, Wlo);

    dim3 grid(BB * (TT / 64));   // 8192 blocks x 4 waves; wave = 16 t
    dim3 block(256);
    rpg_main<<<grid, block, 0, stream>>>(x, Whi, Wlo, out);
}

// Round 8
// 60.673 us; speedup vs baseline: 1.3493x; 1.3493x over previous
//
#include <hip/hip_runtime.h>

#define BB 64
#define CC 64
#define TT 8192
#define NB 8

typedef __attribute__((ext_vector_type(8))) short bf16x8;
typedef __attribute__((ext_vector_type(4))) float f32x4;
typedef __attribute__((ext_vector_type(4))) int i32x4;

union I4B8 { i32x4 i; bf16x8 b; };

__device__ __forceinline__ unsigned short f32_to_bf16_rn(float f) {
    unsigned u = __float_as_uint(f);
    unsigned r = (u + 0x7FFFu + ((u >> 16) & 1u)) >> 16;
    return (unsigned short)r;
}
__device__ __forceinline__ float bf16_to_f32(unsigned short h) {
    return __uint_as_float(((unsigned)h) << 16);
}

// ---- prep: Wf in MFMA A-fragment order --------------------------------------
// slot = ((mt*2+ks)*2+h)*64 + lane ; Wf[slot*8 + j] = W_h[p][c]
//   p = mt*16 + (lane&15), c = ks*32 + (lane>>4)*8 + j
//   W (p<32) = scaled E, (p>=32) = F ; h=0 hi (rn), h=1 lo (rn of residual)
__global__ __launch_bounds__(256) void rpg_prep(
    const float* __restrict__ sigma, const float* __restrict__ rho,
    const float* __restrict__ E, const float* __restrict__ F,
    unsigned short* __restrict__ Wf)
{
    const int idx = blockIdx.x * 256 + threadIdx.x;
    if (idx >= 8192) return;
    const int j    = idx & 7;
    const int slot = idx >> 3;
    const int lane = slot & 63;
    const int h    = (slot >> 6) & 1;
    const int ks   = (slot >> 7) & 1;
    const int mt   = (slot >> 8) & 3;
    const int p = mt * 16 + (lane & 15);
    const int c = ks * 32 + (lane >> 4) * 8 + j;
    float val;
    if (p < 32) {
        const int r = p >> 3, n = p & 7;
        const float es = 8.0f / (1e-5f + fabsf(sigma[r]));
        const float fs = 8.0f / (1e-5f + fabsf(rho[r]));
        val = E[r * (CC * NB) + c * NB + n] * (es * fs * 0.25f);
    } else {
        const int r = (p - 32) >> 3, n = p & 7;
        val = F[r * (CC * NB) + c * NB + n];
    }
    const unsigned short hi = f32_to_bf16_rn(val);
    Wf[idx] = (h == 0) ? hi : f32_to_bf16_rn(val - bf16_to_f32(hi));
}

// ---- main: block = 64 t staged in LDS; wave = 16 t, all 64 output rows ------
// LDS: xh [64 t][8 groups x 16B, group g stored at g^(t&7)] = 8 KB; xl same.
__global__ __launch_bounds__(256, 8) void rpg_main(
    const float* __restrict__ x,
    const unsigned short* __restrict__ Wf,
    float* __restrict__ out)
{
    __shared__ __align__(16) char smem[16384];
    char* xhs = smem;
    char* xls = smem + 8192;

    const int tid  = threadIdx.x;
    const int w    = tid >> 6;
    const int lane = tid & 63;
    const int am   = lane & 15;      // t within wave tile; MFMA col
    const int ag   = lane >> 4;      // k-group

    const int b  = blockIdx.x >> 7;
    const int t0 = (blockIdx.x & 127) * 64;       // block's 64-t window

    // ---- stage: thread = column t0+lane, channels [w*16, w*16+16) -----------
    {
        const float* xcol = x + b * (CC * TT) + t0 + lane;
        unsigned hw[8], lw[8];
        #pragma unroll
        for (int k = 0; k < 8; ++k) {
            const int c = w * 16 + 2 * k;
            const float f0 = xcol[(c    ) * TT];
            const float f1 = xcol[(c + 1) * TT];
            const unsigned u0 = __float_as_uint(f0), u1 = __float_as_uint(f1);
            hw[k] = (u0 >> 16) | (u1 & 0xFFFF0000u);
            const float h0 = __uint_as_float(u0 & 0xFFFF0000u);
            const float h1 = __uint_as_float(u1 & 0xFFFF0000u);
            lw[k] = (__float_as_uint(f0 - h0) >> 16) | (__float_as_uint(f1 - h1) & 0xFFFF0000u);
        }
        const int sw = lane & 7;
        char* hb = xhs + lane * 128;
        char* lb = xls + lane * 128;
        *(i32x4*)(hb + (((2 * w    ) ^ sw) * 16)) = (i32x4){(int)hw[0], (int)hw[1], (int)hw[2], (int)hw[3]};
        *(i32x4*)(hb + (((2 * w + 1) ^ sw) * 16)) = (i32x4){(int)hw[4], (int)hw[5], (int)hw[6], (int)hw[7]};
        *(i32x4*)(lb + (((2 * w    ) ^ sw) * 16)) = (i32x4){(int)lw[0], (int)lw[1], (int)lw[2], (int)lw[3]};
        *(i32x4*)(lb + (((2 * w + 1) ^ sw) * 16)) = (i32x4){(int)lw[4], (int)lw[5], (int)lw[6], (int)lw[7]};
    }
    __syncthreads();

    // ---- B-frags from LDS (reused across all 4 M-tiles): 4x ds_read_b128 ----
    bf16x8 xh[2], xl[2];
    {
        const int trow = w * 16 + am;
        const int sw   = trow & 7;
        #pragma unroll
        for (int ks = 0; ks < 2; ++ks) {
            const int g  = (ks * 4 + ag) ^ sw;
            const int off = trow * 128 + g * 16;
            xh[ks] = ((const I4B8*)(xhs + off))->b;
            xl[ks] = ((const I4B8*)(xls + off))->b;
        }
    }

    // ---- GEMM: acc[mt][r] = Y[p = mt*16 + ag*4 + r][t0 + w*16 + am] ---------
    f32x4 acc[4];
    #pragma unroll
    for (int mt = 0; mt < 4; ++mt) {
        acc[mt] = (f32x4){0.0f, 0.0f, 0.0f, 0.0f};
        #pragma unroll
        for (int ks = 0; ks < 2; ++ks) {
            const bf16x8 wh = *(const bf16x8*)(Wf + (((mt * 2 + ks) * 2 + 0) * 64 + lane) * 8);
            const bf16x8 wl = *(const bf16x8*)(Wf + (((mt * 2 + ks) * 2 + 1) * 64 + lane) * 8);
            acc[mt] = __builtin_amdgcn_mfma_f32_16x16x32_bf16(wh, xh[ks], acc[mt], 0, 0, 0);
            acc[mt] = __builtin_amdgcn_mfma_f32_16x16x32_bf16(wh, xl[ks], acc[mt], 0, 0, 0);
            acc[mt] = __builtin_amdgcn_mfma_f32_16x16x32_bf16(wl, xh[ks], acc[mt], 0, 0, 0);
        }
    }

    // ---- in-register epilogue (verified lane algebra, R7) -------------------
    const bool ra0 = (ag & 2) == 0;
    const bool qlo = (ag & 1) == 0;

    float pA[4], pB[4], pC[4], pD[4];
    #pragma unroll
    for (int i = 0; i < 4; ++i) {
        pA[i] = __shfl_xor(acc[0][i], 32);
        pB[i] = __shfl_xor(acc[1][i], 32);
        pC[i] = __shfl_xor(acc[2][i], 32);
        pD[i] = __shfl_xor(acc[3][i], 32);
    }

    float xe_[4][2];
    #pragma unroll
    for (int e = 0; e < 2; ++e) {
        xe_[0][e] = ra0 ? acc[0][e] : pA[2 + e];
        xe_[1][e] = ra0 ? pA[e]     : acc[0][2 + e];
        xe_[2][e] = ra0 ? acc[1][e] : pB[2 + e];
        xe_[3][e] = ra0 ? pB[e]     : acc[1][2 + e];
    }

    float xfq0[4], xfq1[4], xfq2[4], xfq3[4];
    #pragma unroll
    for (int i = 0; i < 4; ++i) {
        xfq0[i] = ra0 ? acc[2][i] : pC[i];
        xfq1[i] = ra0 ? pC[i]     : acc[2][i];
        xfq2[i] = ra0 ? acc[3][i] : pD[i];
        xfq3[i] = ra0 ? pD[i]     : acc[3][i];
    }
    float xfo0[4], xfo1[4], xfo2[4], xfo3[4];
    #pragma unroll
    for (int i = 0; i < 4; ++i) {
        xfo0[i] = __shfl_xor(xfq0[i], 16);
        xfo1[i] = __shfl_xor(xfq1[i], 16);
        xfo2[i] = __shfl_xor(xfq2[i], 16);
        xfo3[i] = __shfl_xor(xfq3[i], 16);
    }
    float xfL[4][4], xfH[4][4];
    #pragma unroll
    for (int i = 0; i < 4; ++i) {
        xfL[0][i] = qlo ? xfq0[i] : xfo0[i];  xfH[0][i] = qlo ? xfo0[i] : xfq0[i];
        xfL[1][i] = qlo ? xfq1[i] : xfo1[i];  xfH[1][i] = qlo ? xfo1[i] : xfq1[i];
        xfL[2][i] = qlo ? xfq2[i] : xfo2[i];  xfH[2][i] = qlo ? xfo2[i] : xfq2[i];
        xfL[3][i] = qlo ? xfq3[i] : xfo3[i];  xfH[3][i] = qlo ? xfo3[i] : xfq3[i];
    }

    float z[2][8];
    float pm = 0.0f;
    #pragma unroll
    for (int e = 0; e < 2; ++e) {
        #pragma unroll
        for (int m = 0; m < 4; ++m) {
            float a = xe_[0][e] * xfL[0][m];
            a = fmaf(xe_[1][e], xfL[1][m], a);
            a = fmaf(xe_[2][e], xfL[2][m], a);
            a = fmaf(xe_[3][e], xfL[3][m], a);
            float s = __builtin_amdgcn_sqrtf(fabsf(a) + 0.01f) - 0.1f;
            float v = copysignf(s, a);
            z[e][m] = v;
            pm = fmaxf(pm, fabsf(v));
        }
        #pragma unroll
        for (int m = 0; m < 4; ++m) {
            float a = xe_[0][e] * xfH[0][m];
            a = fmaf(xe_[1][e], xfH[1][m], a);
            a = fmaf(xe_[2][e], xfH[2][m], a);
            a = fmaf(xe_[3][e], xfH[3][m], a);
            float s = __builtin_amdgcn_sqrtf(fabsf(a) + 0.01f) - 0.1f;
            float v = copysignf(s, a);
            z[e][4 + m] = v;
            pm = fmaxf(pm, fabsf(v));
        }
    }

    pm = fmaxf(pm, __shfl_xor(pm, 16));
    pm = fmaxf(pm, __shfl_xor(pm, 32));
    const float rinv = __builtin_amdgcn_rcpf(pm + 1e-5f);

    const int nbase = (qlo ? 0 : 4) + (ra0 ? 0 : 2);
    float* ob = out + b * (64 * TT) + t0 + w * 16 + am;
    #pragma unroll
    for (int e = 0; e < 2; ++e)
        #pragma unroll
        for (int m = 0; m < 8; ++m)
            ob[((nbase + e) * NB + m) * TT] = z[e][m] * rinv;
}

extern "C" void kernel_launch(void* const* d_in, const int* in_sizes, int n_in,
                              void* d_out, int out_size, void* d_ws, size_t ws_size,
                              hipStream_t stream) {
    const float* x     = (const float*)d_in[0];
    const float* sigma = (const float*)d_in[1];
    const float* rho   = (const float*)d_in[2];
    const float* E     = (const float*)d_in[3];
    const float* F     = (const float*)d_in[4];
    float* out = (float*)d_out;

    unsigned short* Wf = (unsigned short*)d_ws;   // 8192 shorts = 16 KB

    rpg_prep<<<32, 256, 0, stream>>>(sigma, rho, E, F, Wf);

    dim3 grid(BB * (TT / 64));   // 8192 blocks; 4 waves x 16 t each
    dim3 block(256);
    rpg_main<<<grid, block, 0, stream>>>(x, Wf, out);
}

// Round 9
// 52.006 us; speedup vs baseline: 1.5742x; 1.1666x over previous
//
#include <hip/hip_runtime.h>

#define BB 64
#define CC 64
#define TT 8192
#define NB 8

typedef __attribute__((ext_vector_type(8))) short bf16x8;
typedef __attribute__((ext_vector_type(4))) float f32x4;
typedef __attribute__((ext_vector_type(4))) int i32x4;

union I4B8 { i32x4 i; bf16x8 b; };

__device__ __forceinline__ unsigned short f32_to_bf16_rn(float f) {
    unsigned u = __float_as_uint(f);
    unsigned r = (u + 0x7FFFu + ((u >> 16) & 1u)) >> 16;
    return (unsigned short)r;
}
__device__ __forceinline__ float bf16_to_f32(unsigned short h) {
    return __uint_as_float(((unsigned)h) << 16);
}

// ---- prep: Wf in MFMA A-fragment order --------------------------------------
// slot = ((mt*2+ks)*2+h)*64 + lane ; Wf[slot*8 + j] = W_h[p][c]
//   p = mt*16 + (lane&15), c = ks*32 + (lane>>4)*8 + j
//   W (p<32) = scaled E, (p>=32) = F ; h=0 hi (rn), h=1 lo (rn of residual)
__global__ __launch_bounds__(256) void rpg_prep(
    const float* __restrict__ sigma, const float* __restrict__ rho,
    const float* __restrict__ E, const float* __restrict__ F,
    unsigned short* __restrict__ Wf)
{
    const int idx = blockIdx.x * 256 + threadIdx.x;
    if (idx >= 8192) return;
    const int j    = idx & 7;
    const int slot = idx >> 3;
    const int lane = slot & 63;
    const int h    = (slot >> 6) & 1;
    const int ks   = (slot >> 7) & 1;
    const int mt   = (slot >> 8) & 3;
    const int p = mt * 16 + (lane & 15);
    const int c = ks * 32 + (lane >> 4) * 8 + j;
    float val;
    if (p < 32) {
        const int r = p >> 3, n = p & 7;
        const float es = 8.0f / (1e-5f + fabsf(sigma[r]));
        const float fs = 8.0f / (1e-5f + fabsf(rho[r]));
        val = E[r * (CC * NB) + c * NB + n] * (es * fs * 0.25f);
    } else {
        const int r = (p - 32) >> 3, n = p & 7;
        val = F[r * (CC * NB) + c * NB + n];
    }
    const unsigned short hi = f32_to_bf16_rn(val);
    Wf[idx] = (h == 0) ? hi : f32_to_bf16_rn(val - bf16_to_f32(hi));
}

// ---- main: block = 64 t; wave = 16 t, all 64 output rows --------------------
// LDS: [0,16K)   W fragments (copied once per block, ds_read_b128 thereafter)
//      [16K,24K) xh  [64 t][8 groups x 16B, group g stored at g^(t&7)]
//      [24K,32K) xl  same
__global__ __launch_bounds__(256, 4) void rpg_main(
    const float* __restrict__ x,
    const unsigned short* __restrict__ Wf,
    float* __restrict__ out)
{
    __shared__ __align__(16) char smem[32768];
    char* wsl = smem;
    char* xhs = smem + 16384;
    char* xls = smem + 24576;

    const int tid  = threadIdx.x;
    const int w    = tid >> 6;
    const int lane = tid & 63;
    const int am   = lane & 15;      // t within wave tile; MFMA col
    const int ag   = lane >> 4;      // k-group

    const int b  = blockIdx.x >> 7;
    const int t0 = (blockIdx.x & 127) * 64;       // block's 64-t window

    // ---- cooperative W copy: 16 KB global(L2) -> LDS, contiguous b128 -------
    #pragma unroll
    for (int k = 0; k < 4; ++k) {
        const int off = k * 4096 + tid * 16;
        *(i32x4*)(wsl + off) = *(const i32x4*)((const char*)Wf + off);
    }

    // ---- stage x: thread = column t0+lane, channels [w*16, w*16+16) ---------
    {
        const float* xcol = x + b * (CC * TT) + t0 + lane;
        unsigned hw[8], lw[8];
        #pragma unroll
        for (int k = 0; k < 8; ++k) {
            const int c = w * 16 + 2 * k;
            const float f0 = xcol[(c    ) * TT];
            const float f1 = xcol[(c + 1) * TT];
            const unsigned u0 = __float_as_uint(f0), u1 = __float_as_uint(f1);
            hw[k] = (u0 >> 16) | (u1 & 0xFFFF0000u);
            const float h0 = __uint_as_float(u0 & 0xFFFF0000u);
            const float h1 = __uint_as_float(u1 & 0xFFFF0000u);
            lw[k] = (__float_as_uint(f0 - h0) >> 16) | (__float_as_uint(f1 - h1) & 0xFFFF0000u);
        }
        const int sw = lane & 7;
        char* hb = xhs + lane * 128;
        char* lb = xls + lane * 128;
        *(i32x4*)(hb + (((2 * w    ) ^ sw) * 16)) = (i32x4){(int)hw[0], (int)hw[1], (int)hw[2], (int)hw[3]};
        *(i32x4*)(hb + (((2 * w + 1) ^ sw) * 16)) = (i32x4){(int)hw[4], (int)hw[5], (int)hw[6], (int)hw[7]};
        *(i32x4*)(lb + (((2 * w    ) ^ sw) * 16)) = (i32x4){(int)lw[0], (int)lw[1], (int)lw[2], (int)lw[3]};
        *(i32x4*)(lb + (((2 * w + 1) ^ sw) * 16)) = (i32x4){(int)lw[4], (int)lw[5], (int)lw[6], (int)lw[7]};
    }
    __syncthreads();

    // ---- B-frags from LDS (reused across all 4 M-tiles) ---------------------
    bf16x8 xh[2], xl[2];
    {
        const int trow = w * 16 + am;
        const int sw   = trow & 7;
        #pragma unroll
        for (int ks = 0; ks < 2; ++ks) {
            const int g   = (ks * 4 + ag) ^ sw;
            const int off = trow * 128 + g * 16;
            xh[ks] = ((const I4B8*)(xhs + off))->b;
            xl[ks] = ((const I4B8*)(xls + off))->b;
        }
    }

    // ---- GEMM: acc[mt][r] = Y[p = mt*16 + ag*4 + r][t0 + w*16 + am] ---------
    f32x4 acc[4];
    #pragma unroll
    for (int mt = 0; mt < 4; ++mt) {
        acc[mt] = (f32x4){0.0f, 0.0f, 0.0f, 0.0f};
        #pragma unroll
        for (int ks = 0; ks < 2; ++ks) {
            const int fh = ((mt * 2 + ks) * 2 + 0) * 1024 + lane * 16;
            const int fl = ((mt * 2 + ks) * 2 + 1) * 1024 + lane * 16;
            const bf16x8 wh = ((const I4B8*)(wsl + fh))->b;
            const bf16x8 wl = ((const I4B8*)(wsl + fl))->b;
            acc[mt] = __builtin_amdgcn_mfma_f32_16x16x32_bf16(wh, xh[ks], acc[mt], 0, 0, 0);
            acc[mt] = __builtin_amdgcn_mfma_f32_16x16x32_bf16(wh, xl[ks], acc[mt], 0, 0, 0);
            acc[mt] = __builtin_amdgcn_mfma_f32_16x16x32_bf16(wl, xh[ks], acc[mt], 0, 0, 0);
        }
    }

    // ---- in-register epilogue (verified lane algebra, R7/R8) ----------------
    const bool ra0 = (ag & 2) == 0;
    const bool qlo = (ag & 1) == 0;

    float pA[4], pB[4], pC[4], pD[4];
    #pragma unroll
    for (int i = 0; i < 4; ++i) {
        pA[i] = __shfl_xor(acc[0][i], 32);
        pB[i] = __shfl_xor(acc[1][i], 32);
        pC[i] = __shfl_xor(acc[2][i], 32);
        pD[i] = __shfl_xor(acc[3][i], 32);
    }

    float xe_[4][2];
    #pragma unroll
    for (int e = 0; e < 2; ++e) {
        xe_[0][e] = ra0 ? acc[0][e] : pA[2 + e];
        xe_[1][e] = ra0 ? pA[e]     : acc[0][2 + e];
        xe_[2][e] = ra0 ? acc[1][e] : pB[2 + e];
        xe_[3][e] = ra0 ? pB[e]     : acc[1][2 + e];
    }

    float xfq0[4], xfq1[4], xfq2[4], xfq3[4];
    #pragma unroll
    for (int i = 0; i < 4; ++i) {
        xfq0[i] = ra0 ? acc[2][i] : pC[i];
        xfq1[i] = ra0 ? pC[i]     : acc[2][i];
        xfq2[i] = ra0 ? acc[3][i] : pD[i];
        xfq3[i] = ra0 ? pD[i]     : acc[3][i];
    }
    float xfo0[4], xfo1[4], xfo2[4], xfo3[4];
    #pragma unroll
    for (int i = 0; i < 4; ++i) {
        xfo0[i] = __shfl_xor(xfq0[i], 16);
        xfo1[i] = __shfl_xor(xfq1[i], 16);
        xfo2[i] = __shfl_xor(xfq2[i], 16);
        xfo3[i] = __shfl_xor(xfq3[i], 16);
    }
    float xfL[4][4], xfH[4][4];
    #pragma unroll
    for (int i = 0; i < 4; ++i) {
        xfL[0][i] = qlo ? xfq0[i] : xfo0[i];  xfH[0][i] = qlo ? xfo0[i] : xfq0[i];
        xfL[1][i] = qlo ? xfq1[i] : xfo1[i];  xfH[1][i] = qlo ? xfo1[i] : xfq1[i];
        xfL[2][i] = qlo ? xfq2[i] : xfo2[i];  xfH[2][i] = qlo ? xfo2[i] : xfq2[i];
        xfL[3][i] = qlo ? xfq3[i] : xfo3[i];  xfH[3][i] = qlo ? xfo3[i] : xfq3[i];
    }

    float z[2][8];
    float pm = 0.0f;
    #pragma unroll
    for (int e = 0; e < 2; ++e) {
        #pragma unroll
        for (int m = 0; m < 4; ++m) {
            float a = xe_[0][e] * xfL[0][m];
            a = fmaf(xe_[1][e], xfL[1][m], a);
            a = fmaf(xe_[2][e], xfL[2][m], a);
            a = fmaf(xe_[3][e], xfL[3][m], a);
            float s = __builtin_amdgcn_sqrtf(fabsf(a) + 0.01f) - 0.1f;
            float v = copysignf(s, a);
            z[e][m] = v;
            pm = fmaxf(pm, fabsf(v));
        }
        #pragma unroll
        for (int m = 0; m < 4; ++m) {
            float a = xe_[0][e] * xfH[0][m];
            a = fmaf(xe_[1][e], xfH[1][m], a);
            a = fmaf(xe_[2][e], xfH[2][m], a);
            a = fmaf(xe_[3][e], xfH[3][m], a);
            float s = __builtin_amdgcn_sqrtf(fabsf(a) + 0.01f) - 0.1f;
            float v = copysignf(s, a);
            z[e][4 + m] = v;
            pm = fmaxf(pm, fabsf(v));
        }
    }

    pm = fmaxf(pm, __shfl_xor(pm, 16));
    pm = fmaxf(pm, __shfl_xor(pm, 32));
    const float rinv = __builtin_amdgcn_rcpf(pm + 1e-5f);

    const int nbase = (qlo ? 0 : 4) + (ra0 ? 0 : 2);
    float* ob = out + b * (64 * TT) + t0 + w * 16 + am;
    #pragma unroll
    for (int e = 0; e < 2; ++e)
        #pragma unroll
        for (int m = 0; m < 8; ++m)
            ob[((nbase + e) * NB + m) * TT] = z[e][m] * rinv;
}

extern "C" void kernel_launch(void* const* d_in, const int* in_sizes, int n_in,
                              void* d_out, int out_size, void* d_ws, size_t ws_size,
                              hipStream_t stream) {
    const float* x     = (const float*)d_in[0];
    const float* sigma = (const float*)d_in[1];
    const float* rho   = (const float*)d_in[2];
    const float* E     = (const float*)d_in[3];
    const float* F     = (const float*)d_in[4];
    float* out = (float*)d_out;

    unsigned short* Wf = (unsigned short*)d_ws;   // 8192 shorts = 16 KB

    rpg_prep<<<32, 256, 0, stream>>>(sigma, rho, E, F, Wf);

    dim3 grid(BB * (TT / 64));   // 8192 blocks; 4 waves x 16 t each
    dim3 block(256);
    rpg_main<<<grid, block, 0, stream>>>(x, Wf, out);
}

// Round 10
// 49.838 us; speedup vs baseline: 1.6427x; 1.0435x over previous
//
#include <hip/hip_runtime.h>

#define CC 64
#define TT 8192
#define NB 8
#define NWIN 8192          // 64 b * 128 windows of 64 t
#define GRID 768           // 3 blocks/CU * 256 CUs

typedef __attribute__((ext_vector_type(8))) short bf16x8;
typedef __attribute__((ext_vector_type(4))) float f32x4;
typedef __attribute__((ext_vector_type(4))) int i32x4;

union I4B8 { i32x4 i; bf16x8 b; };

__device__ __forceinline__ unsigned short f32_to_bf16_rn(float f) {
    unsigned u = __float_as_uint(f);
    unsigned r = (u + 0x7FFFu + ((u >> 16) & 1u)) >> 16;
    return (unsigned short)r;
}
__device__ __forceinline__ float bf16_to_f32(unsigned short h) {
    return __uint_as_float(((unsigned)h) << 16);
}

// LDS: [0,16K) W frags; [16K,32K) xbuf0 (xh 8K + xl 8K); [32K,48K) xbuf1
__global__ __launch_bounds__(256, 3) void rpg_fused(
    const float* __restrict__ x,
    const float* __restrict__ sigma,
    const float* __restrict__ rho,
    const float* __restrict__ E,
    const float* __restrict__ F,
    float* __restrict__ out)
{
    __shared__ __align__(16) char smem[49152];
    char* wsl = smem;

    const int tid  = threadIdx.x;
    const int w    = tid >> 6;
    const int lane = tid & 63;
    const int am   = lane & 15;
    const int ag   = lane >> 4;

    // ---- build W fragments in LDS, once per block ---------------------------
    // thread tid <-> (r = tid>>6, c = tid&63); loads E/F [r][c][0..8) contiguous.
    // frag byte offset for (p, c, h): mt=p>>4, am=p&15, ks=c>>5, ag=(c>>3)&3,
    //   j=c&7 -> (((mt*2+ks)*2+h)*64 + ag*16+am)*16 + j*2
    {
        const int r = tid >> 6;
        const int c = tid & 63;
        const float g = (8.0f / (1e-5f + fabsf(sigma[r]))) *
                        (8.0f / (1e-5f + fabsf(rho[r]))) * 0.25f;
        const int wks = c >> 5, wag = (c >> 3) & 3, wj = c & 7;
        const float4 e0 = *(const float4*)(E + (r * 64 + c) * 8);
        const float4 e1 = *(const float4*)(E + (r * 64 + c) * 8 + 4);
        const float4 fv0 = *(const float4*)(F + (r * 64 + c) * 8);
        const float4 fv1 = *(const float4*)(F + (r * 64 + c) * 8 + 4);
        const float ev[8] = {e0.x, e0.y, e0.z, e0.w, e1.x, e1.y, e1.z, e1.w};
        const float fv[8] = {fv0.x, fv0.y, fv0.z, fv0.w, fv1.x, fv1.y, fv1.z, fv1.w};
        #pragma unroll
        for (int n = 0; n < 8; ++n) {
            {   // E side: p = r*8+n (scaled)
                const int p = r * 8 + n;
                const float val = ev[n] * g;
                const unsigned short hi = f32_to_bf16_rn(val);
                const unsigned short lo = f32_to_bf16_rn(val - bf16_to_f32(hi));
                const int mt = p >> 4, pam = p & 15;
                char* base = wsl + ((((mt * 2 + wks) * 2 + 0) * 64 + wag * 16 + pam) << 4) + wj * 2;
                *(unsigned short*)base = hi;
                *(unsigned short*)(base + 1024) = lo;
            }
            {   // F side: p = 32 + r*8+n (unscaled)
                const int p = 32 + r * 8 + n;
                const float val = fv[n];
                const unsigned short hi = f32_to_bf16_rn(val);
                const unsigned short lo = f32_to_bf16_rn(val - bf16_to_f32(hi));
                const int mt = p >> 4, pam = p & 15;
                char* base = wsl + ((((mt * 2 + wks) * 2 + 0) * 64 + wag * 16 + pam) << 4) + wj * 2;
                *(unsigned short*)base = hi;
                *(unsigned short*)(base + 1024) = lo;
            }
        }
    }

    // ---- prefetch window 0 --------------------------------------------------
    int wid = blockIdx.x;
    float f[16];
    {
        const int b = wid >> 7, t0 = (wid & 127) << 6;
        const float* xcol = x + b * (CC * TT) + t0 + lane;
        #pragma unroll
        for (int k = 0; k < 16; ++k) f[k] = xcol[(w * 16 + k) * TT];
    }

    int ibuf = 0;
    const bool ra0 = (ag & 2) == 0;
    const bool qlo = (ag & 1) == 0;

    while (wid < NWIN) {
        char* xbuf = ibuf ? (smem + 32768) : (smem + 16384);

        // ---- convert f -> bf16 hi/lo, ds_write with XOR swizzle -------------
        {
            unsigned hw[8], lw[8];
            #pragma unroll
            for (int k = 0; k < 8; ++k) {
                const unsigned u0 = __float_as_uint(f[2 * k]);
                const unsigned u1 = __float_as_uint(f[2 * k + 1]);
                hw[k] = (u0 >> 16) | (u1 & 0xFFFF0000u);
                const float h0 = __uint_as_float(u0 & 0xFFFF0000u);
                const float h1 = __uint_as_float(u1 & 0xFFFF0000u);
                lw[k] = (__float_as_uint(f[2 * k] - h0) >> 16) |
                        (__float_as_uint(f[2 * k + 1] - h1) & 0xFFFF0000u);
            }
            const int sw = lane & 7;
            char* hb = xbuf + lane * 128;
            char* lb = xbuf + 8192 + lane * 128;
            *(i32x4*)(hb + (((2 * w    ) ^ sw) * 16)) = (i32x4){(int)hw[0], (int)hw[1], (int)hw[2], (int)hw[3]};
            *(i32x4*)(hb + (((2 * w + 1) ^ sw) * 16)) = (i32x4){(int)hw[4], (int)hw[5], (int)hw[6], (int)hw[7]};
            *(i32x4*)(lb + (((2 * w    ) ^ sw) * 16)) = (i32x4){(int)lw[0], (int)lw[1], (int)lw[2], (int)lw[3]};
            *(i32x4*)(lb + (((2 * w + 1) ^ sw) * 16)) = (i32x4){(int)lw[4], (int)lw[5], (int)lw[6], (int)lw[7]};
        }

        const int b  = wid >> 7;
        const int t0 = (wid & 127) << 6;
        const int next = wid + GRID;

        __syncthreads();

        // ---- B-frags from LDS (reused across the 4 M-tiles) -----------------
        bf16x8 xh[2], xl[2];
        {
            const int trow = w * 16 + am;
            const int sw   = trow & 7;
            #pragma unroll
            for (int ks = 0; ks < 2; ++ks) {
                const int g2  = (ks * 4 + ag) ^ sw;
                const int off = trow * 128 + g2 * 16;
                xh[ks] = ((const I4B8*)(xbuf + off))->b;
                xl[ks] = ((const I4B8*)(xbuf + 8192 + off))->b;
            }
        }

        // ---- prefetch next window (after barrier: flies under compute) ------
        if (next < NWIN) {
            const int nbx = next >> 7, nt0 = (next & 127) << 6;
            const float* xcol = x + nbx * (CC * TT) + nt0 + lane;
            #pragma unroll
            for (int k = 0; k < 16; ++k) f[k] = xcol[(w * 16 + k) * TT];
        }

        // ---- GEMM: acc[mt][r] = Y[p = mt*16 + ag*4 + r][t0 + w*16 + am] -----
        f32x4 acc[4];
        #pragma unroll
        for (int mt = 0; mt < 4; ++mt) {
            acc[mt] = (f32x4){0.0f, 0.0f, 0.0f, 0.0f};
            #pragma unroll
            for (int ks = 0; ks < 2; ++ks) {
                const int fb = ((mt * 2 + ks) * 2) * 1024 + lane * 16;
                const bf16x8 wh = ((const I4B8*)(wsl + fb))->b;
                const bf16x8 wl = ((const I4B8*)(wsl + fb + 1024))->b;
                acc[mt] = __builtin_amdgcn_mfma_f32_16x16x32_bf16(wh, xh[ks], acc[mt], 0, 0, 0);
                acc[mt] = __builtin_amdgcn_mfma_f32_16x16x32_bf16(wh, xl[ks], acc[mt], 0, 0, 0);
                acc[mt] = __builtin_amdgcn_mfma_f32_16x16x32_bf16(wl, xh[ks], acc[mt], 0, 0, 0);
            }
        }

        // ---- in-register epilogue (verified lane algebra) -------------------
        float pA[4], pB[4], pC[4], pD[4];
        #pragma unroll
        for (int i = 0; i < 4; ++i) {
            pA[i] = __shfl_xor(acc[0][i], 32);
            pB[i] = __shfl_xor(acc[1][i], 32);
            pC[i] = __shfl_xor(acc[2][i], 32);
            pD[i] = __shfl_xor(acc[3][i], 32);
        }

        float xe_[4][2];
        #pragma unroll
        for (int e = 0; e < 2; ++e) {
            xe_[0][e] = ra0 ? acc[0][e] : pA[2 + e];
            xe_[1][e] = ra0 ? pA[e]     : acc[0][2 + e];
            xe_[2][e] = ra0 ? acc[1][e] : pB[2 + e];
            xe_[3][e] = ra0 ? pB[e]     : acc[1][2 + e];
        }

        float xfq0[4], xfq1[4], xfq2[4], xfq3[4];
        #pragma unroll
        for (int i = 0; i < 4; ++i) {
            xfq0[i] = ra0 ? acc[2][i] : pC[i];
            xfq1[i] = ra0 ? pC[i]     : acc[2][i];
            xfq2[i] = ra0 ? acc[3][i] : pD[i];
            xfq3[i] = ra0 ? pD[i]     : acc[3][i];
        }
        float xfo0[4], xfo1[4], xfo2[4], xfo3[4];
        #pragma unroll
        for (int i = 0; i < 4; ++i) {
            xfo0[i] = __shfl_xor(xfq0[i], 16);
            xfo1[i] = __shfl_xor(xfq1[i], 16);
            xfo2[i] = __shfl_xor(xfq2[i], 16);
            xfo3[i] = __shfl_xor(xfq3[i], 16);
        }
        float xfL[4][4], xfH[4][4];
        #pragma unroll
        for (int i = 0; i < 4; ++i) {
            xfL[0][i] = qlo ? xfq0[i] : xfo0[i];  xfH[0][i] = qlo ? xfo0[i] : xfq0[i];
            xfL[1][i] = qlo ? xfq1[i] : xfo1[i];  xfH[1][i] = qlo ? xfo1[i] : xfq1[i];
            xfL[2][i] = qlo ? xfq2[i] : xfo2[i];  xfH[2][i] = qlo ? xfo2[i] : xfq2[i];
            xfL[3][i] = qlo ? xfq3[i] : xfo3[i];  xfH[3][i] = qlo ? xfo3[i] : xfq3[i];
        }

        float z[2][8];
        float pm = 0.0f;
        #pragma unroll
        for (int e = 0; e < 2; ++e) {
            #pragma unroll
            for (int m = 0; m < 4; ++m) {
                float a = xe_[0][e] * xfL[0][m];
                a = fmaf(xe_[1][e], xfL[1][m], a);
                a = fmaf(xe_[2][e], xfL[2][m], a);
                a = fmaf(xe_[3][e], xfL[3][m], a);
                float s = __builtin_amdgcn_sqrtf(fabsf(a) + 0.01f) - 0.1f;
                float v = copysignf(s, a);
                z[e][m] = v;
                pm = fmaxf(pm, fabsf(v));
            }
            #pragma unroll
            for (int m = 0; m < 4; ++m) {
                float a = xe_[0][e] * xfH[0][m];
                a = fmaf(xe_[1][e], xfH[1][m], a);
                a = fmaf(xe_[2][e], xfH[2][m], a);
                a = fmaf(xe_[3][e], xfH[3][m], a);
                float s = __builtin_amdgcn_sqrtf(fabsf(a) + 0.01f) - 0.1f;
                float v = copysignf(s, a);
                z[e][4 + m] = v;
                pm = fmaxf(pm, fabsf(v));
            }
        }

        pm = fmaxf(pm, __shfl_xor(pm, 16));
        pm = fmaxf(pm, __shfl_xor(pm, 32));
        const float rinv = __builtin_amdgcn_rcpf(pm + 1e-5f);

        const int nbase = (qlo ? 0 : 4) + (ra0 ? 0 : 2);
        float* ob = out + b * (64 * TT) + t0 + w * 16 + am;
        #pragma unroll
        for (int e = 0; e < 2; ++e)
            #pragma unroll
            for (int m = 0; m < 8; ++m)
                ob[((nbase + e) * NB + m) * TT] = z[e][m] * rinv;

        wid = next;
        ibuf ^= 1;
    }
}

extern "C" void kernel_launch(void* const* d_in, const int* in_sizes, int n_in,
                              void* d_out, int out_size, void* d_ws, size_t ws_size,
                              hipStream_t stream) {
    const float* x     = (const float*)d_in[0];
    const float* sigma = (const float*)d_in[1];
    const float* rho   = (const float*)d_in[2];
    const float* E     = (const float*)d_in[3];
    const float* F     = (const float*)d_in[4];
    float* out = (float*)d_out;

    rpg_fused<<<GRID, 256, 0, stream>>>(x, sigma, rho, E, F, out);
}